// Round 1
// baseline (702.236 us; speedup 1.0000x reference)
//
#include <hip/hip_runtime.h>
#include <math.h>

// Problem dims (fixed by setup_inputs)
#define B_   2
#define NQ   2048
#define NK   4096
#define D_   512
#define H_   8
#define DH   64
#define HID  2048

typedef _Float16 f16;
typedef __attribute__((ext_vector_type(8))) _Float16 f16x8;
typedef __attribute__((ext_vector_type(4))) float f32x4;

__device__ __forceinline__ f16x8 cvt8(f32x4 a, f32x4 b) {
    f16x8 r;
    r[0] = (f16)a[0]; r[1] = (f16)a[1]; r[2] = (f16)a[2]; r[3] = (f16)a[3];
    r[4] = (f16)b[0]; r[5] = (f16)b[1]; r[6] = (f16)b[2]; r[7] = (f16)b[3];
    return r;
}

// ---------------------------------------------------------------------------
// Weight transpose + fp32->fp16 convert:  Wt[n][k] = W[k][n]
// block (32,8), grid (N/32, K/32)
// ---------------------------------------------------------------------------
__global__ __launch_bounds__(256)
void transpose_cvt(const float* __restrict__ W, f16* __restrict__ Wt, int K, int N) {
    __shared__ float t[32][33];
    int tx = threadIdx.x, ty = threadIdx.y;
    int n0 = blockIdx.x * 32, k0 = blockIdx.y * 32;
#pragma unroll
    for (int i = 0; i < 4; i++)
        t[ty + i * 8][tx] = W[(size_t)(k0 + ty + i * 8) * N + n0 + tx];
    __syncthreads();
#pragma unroll
    for (int i = 0; i < 4; i++)
        Wt[(size_t)(n0 + ty + i * 8) * K + k0 + tx] = (f16)t[tx][ty + i * 8];
}

// ---------------------------------------------------------------------------
// GEMM: C[M][N] = A[M][K] @ W[K][N] + bias (+res) (gelu if act)
// A fp32 row-major, Wt fp16 = W^T [N][K].  128x128 tile, BK=32, 256 thr.
// ---------------------------------------------------------------------------
__global__ __launch_bounds__(256)
void gemm_kernel(const float* __restrict__ A, const f16* __restrict__ Wt,
                 const float* __restrict__ bias, const float* __restrict__ res,
                 float* __restrict__ C, int M, int N, int K, int act)
{
    __shared__ f16 As[128 * 40];   // pitch 40 halves = 80B (16B-multiple)
    __shared__ f16 Bs[128 * 40];
    int tid = threadIdx.x;
    int lane = tid & 63, wave = tid >> 6;
    int quad = lane >> 4, ln16 = lane & 15;
    int wm = wave >> 1, wn = wave & 1;
    int bm0 = blockIdx.y * 128, bn0 = blockIdx.x * 128;

    f32x4 acc[4][4];
#pragma unroll
    for (int i = 0; i < 4; i++)
#pragma unroll
        for (int j = 0; j < 4; j++) acc[i][j] = (f32x4){0.f, 0.f, 0.f, 0.f};

    int srow = tid >> 1;
    int scol = (tid & 1) * 16;
    const float* ap = A + (size_t)(bm0 + srow) * K + scol;
    const f16*   wp = Wt + (size_t)(bn0 + srow) * K + scol;
    f16* asd = &As[srow * 40 + scol];
    f16* bsd = &Bs[srow * 40 + scol];

    for (int kt = 0; kt < K; kt += 32) {
        f32x4 a0 = *(const f32x4*)(ap);
        f32x4 a1 = *(const f32x4*)(ap + 4);
        f32x4 a2 = *(const f32x4*)(ap + 8);
        f32x4 a3 = *(const f32x4*)(ap + 12);
        f16x8 w0 = *(const f16x8*)(wp);
        f16x8 w1 = *(const f16x8*)(wp + 8);
        __syncthreads();
        *(f16x8*)(asd)     = cvt8(a0, a1);
        *(f16x8*)(asd + 8) = cvt8(a2, a3);
        *(f16x8*)(bsd)     = w0;
        *(f16x8*)(bsd + 8) = w1;
        __syncthreads();
        f16x8 af[4], bfr[4];
#pragma unroll
        for (int mt = 0; mt < 4; mt++)
            af[mt] = *(const f16x8*)&As[(wm * 64 + mt * 16 + ln16) * 40 + quad * 8];
#pragma unroll
        for (int nt = 0; nt < 4; nt++)
            bfr[nt] = *(const f16x8*)&Bs[(wn * 64 + nt * 16 + ln16) * 40 + quad * 8];
#pragma unroll
        for (int mt = 0; mt < 4; mt++)
#pragma unroll
            for (int nt = 0; nt < 4; nt++)
                acc[mt][nt] = __builtin_amdgcn_mfma_f32_16x16x32_f16(af[mt], bfr[nt], acc[mt][nt], 0, 0, 0);
        ap += 32; wp += 32;
    }

#pragma unroll
    for (int mt = 0; mt < 4; mt++) {
#pragma unroll
        for (int nt = 0; nt < 4; nt++) {
            int row0 = bm0 + wm * 64 + mt * 16 + quad * 4;
            int col  = bn0 + wn * 64 + nt * 16 + ln16;
            float bv = bias[col];
#pragma unroll
            for (int i = 0; i < 4; i++) {
                size_t idx = (size_t)(row0 + i) * N + col;
                float v = acc[mt][nt][i] + bv;
                if (res) v += res[idx];
                if (act) v = 0.5f * v * (1.0f + erff(v * 0.70710678118654752f));
                C[idx] = v;
            }
        }
    }
}

// ---------------------------------------------------------------------------
// LayerNorm over D=512 (biased var, eps=1e-5).  1 block (128 thr) per row.
// ---------------------------------------------------------------------------
__global__ __launch_bounds__(128)
void layernorm_kernel(const float* __restrict__ X, const float* __restrict__ g,
                      const float* __restrict__ bta, float* __restrict__ Y)
{
    __shared__ float red[4];
    int row = blockIdx.x;
    int tid = threadIdx.x;
    const float* x = X + (size_t)row * D_;
    f32x4 v = *(const f32x4*)(x + tid * 4);
    float s  = v[0] + v[1] + v[2] + v[3];
    float ss = v[0] * v[0] + v[1] * v[1] + v[2] * v[2] + v[3] * v[3];
#pragma unroll
    for (int m = 1; m < 64; m <<= 1) {
        s  += __shfl_xor(s, m, 64);
        ss += __shfl_xor(ss, m, 64);
    }
    int wave = tid >> 6, lane = tid & 63;
    if (lane == 0) { red[wave * 2] = s; red[wave * 2 + 1] = ss; }
    __syncthreads();
    s = red[0] + red[2]; ss = red[1] + red[3];
    float mu  = s * (1.0f / D_);
    float var = ss * (1.0f / D_) - mu * mu;
    float inv = rsqrtf(var + 1e-5f);
    f32x4 gv = *(const f32x4*)(g + tid * 4);
    f32x4 bv = *(const f32x4*)(bta + tid * 4);
    f32x4 o;
#pragma unroll
    for (int i = 0; i < 4; i++) o[i] = (v[i] - mu) * inv * gv[i] + bv[i];
    *(f32x4*)(Y + (size_t)row * D_ + tid * 4) = o;
}

// ---------------------------------------------------------------------------
// Flash attention.  Q,K,V: [B, N, 512] fp32 with head h at cols h*64..h*64+63.
// grid (Nq/64, H, B), 256 thr (4 waves x 16 q-rows). Online softmax, d=64.
// ---------------------------------------------------------------------------
__global__ __launch_bounds__(256)
void attention_kernel(const float* __restrict__ Q, const float* __restrict__ Kp,
                      const float* __restrict__ Vp, float* __restrict__ O,
                      int Nq, int Nk)
{
    __shared__ f16 Ks[64 * 72];      // [key][dim], pitch 72
    __shared__ f16 Vt[64 * 72];      // [dim][key], pitch 72
    __shared__ f16 Ps[4][16 * 72];   // per-wave P tile [qrow][key]
    int b = blockIdx.z, h = blockIdx.y;
    int tid = threadIdx.x, lane = tid & 63, wave = tid >> 6;
    int quad = lane >> 4, ln16 = lane & 15;
    int qrow0 = blockIdx.x * 64 + wave * 16;

    // Q fragments (A-layout), scale 1/8 folded in (exact pow2)
    f16x8 aq0, aq1;
    {
        const float* qp = Q + (size_t)(b * Nq + qrow0 + ln16) * D_ + h * DH + quad * 8;
        const float sc = 0.125f;
        f32x4 q0 = *(const f32x4*)(qp);
        f32x4 q1 = *(const f32x4*)(qp + 4);
        f32x4 q2 = *(const f32x4*)(qp + 32);
        f32x4 q3 = *(const f32x4*)(qp + 36);
        aq0 = cvt8(q0 * sc, q1 * sc);
        aq1 = cvt8(q2 * sc, q3 * sc);
    }

    float mrun[4], lrun[4];
    f32x4 oacc[4];
#pragma unroll
    for (int i = 0; i < 4; i++) { mrun[i] = -INFINITY; lrun[i] = 0.f; oacc[i] = (f32x4){0.f, 0.f, 0.f, 0.f}; }

    int skey = tid >> 2, sd = (tid & 3) * 16;
    const float* kp = Kp + (size_t)(b * Nk + skey) * D_ + h * DH + sd;
    const float* vp = Vp + (size_t)(b * Nk + skey) * D_ + h * DH + sd;

    for (int k0 = 0; k0 < Nk; k0 += 64) {
        f32x4 ka = *(const f32x4*)(kp);
        f32x4 kb = *(const f32x4*)(kp + 4);
        f32x4 kc = *(const f32x4*)(kp + 8);
        f32x4 kd = *(const f32x4*)(kp + 12);
        f32x4 va = *(const f32x4*)(vp);
        f32x4 vb = *(const f32x4*)(vp + 4);
        f32x4 vc = *(const f32x4*)(vp + 8);
        f32x4 vd = *(const f32x4*)(vp + 12);
        __syncthreads();
        *(f16x8*)&Ks[skey * 72 + sd]     = cvt8(ka, kb);
        *(f16x8*)&Ks[skey * 72 + sd + 8] = cvt8(kc, kd);
        {
            float vv[16];
            *(f32x4*)&vv[0] = va; *(f32x4*)&vv[4] = vb; *(f32x4*)&vv[8] = vc; *(f32x4*)&vv[12] = vd;
#pragma unroll
            for (int j = 0; j < 16; j++) Vt[(sd + j) * 72 + skey] = (f16)vv[j];
        }
        __syncthreads();

        // S = Q @ K^T  (pre-scaled)
        f32x4 s[4];
#pragma unroll
        for (int nt = 0; nt < 4; nt++) {
            f16x8 b0 = *(const f16x8*)&Ks[(nt * 16 + ln16) * 72 + quad * 8];
            f16x8 b1 = *(const f16x8*)&Ks[(nt * 16 + ln16) * 72 + 32 + quad * 8];
            f32x4 z = (f32x4){0.f, 0.f, 0.f, 0.f};
            z = __builtin_amdgcn_mfma_f32_16x16x32_f16(aq0, b0, z, 0, 0, 0);
            z = __builtin_amdgcn_mfma_f32_16x16x32_f16(aq1, b1, z, 0, 0, 0);
            s[nt] = z;
        }
        // online softmax: rows quad*4+i, cols nt*16+ln16 -> butterfly over 16 lanes
        float mx[4];
#pragma unroll
        for (int i = 0; i < 4; i++)
            mx[i] = fmaxf(fmaxf(s[0][i], s[1][i]), fmaxf(s[2][i], s[3][i]));
#pragma unroll
        for (int m = 1; m < 16; m <<= 1)
#pragma unroll
            for (int i = 0; i < 4; i++) mx[i] = fmaxf(mx[i], __shfl_xor(mx[i], m, 64));
        float alpha[4], rs[4];
#pragma unroll
        for (int i = 0; i < 4; i++) {
            float mn = fmaxf(mrun[i], mx[i]);
            alpha[i] = __expf(mrun[i] - mn);
            mrun[i] = mn;
            rs[i] = 0.f;
        }
#pragma unroll
        for (int nt = 0; nt < 4; nt++)
#pragma unroll
            for (int i = 0; i < 4; i++) {
                float p = __expf(s[nt][i] - mrun[i]);
                s[nt][i] = p;
                rs[i] += p;
            }
#pragma unroll
        for (int m = 1; m < 16; m <<= 1)
#pragma unroll
            for (int i = 0; i < 4; i++) rs[i] += __shfl_xor(rs[i], m, 64);
#pragma unroll
        for (int i = 0; i < 4; i++) lrun[i] = lrun[i] * alpha[i] + rs[i];
#pragma unroll
        for (int dt = 0; dt < 4; dt++)
#pragma unroll
            for (int i = 0; i < 4; i++) oacc[dt][i] *= alpha[i];

        // P: C-layout -> LDS -> A-layout (per-wave region, no barrier needed)
        f16* pw = &Ps[wave][0];
#pragma unroll
        for (int nt = 0; nt < 4; nt++)
#pragma unroll
            for (int i = 0; i < 4; i++)
                pw[(quad * 4 + i) * 72 + nt * 16 + ln16] = (f16)s[nt][i];
        f16x8 ap0 = *(const f16x8*)&pw[ln16 * 72 + quad * 8];
        f16x8 ap1 = *(const f16x8*)&pw[ln16 * 72 + 32 + quad * 8];
#pragma unroll
        for (int dt = 0; dt < 4; dt++) {
            f16x8 bv0 = *(const f16x8*)&Vt[(dt * 16 + ln16) * 72 + quad * 8];
            f16x8 bv1 = *(const f16x8*)&Vt[(dt * 16 + ln16) * 72 + 32 + quad * 8];
            oacc[dt] = __builtin_amdgcn_mfma_f32_16x16x32_f16(ap0, bv0, oacc[dt], 0, 0, 0);
            oacc[dt] = __builtin_amdgcn_mfma_f32_16x16x32_f16(ap1, bv1, oacc[dt], 0, 0, 0);
        }
        kp += (size_t)64 * D_;
        vp += (size_t)64 * D_;
    }

#pragma unroll
    for (int dt = 0; dt < 4; dt++)
#pragma unroll
        for (int i = 0; i < 4; i++) {
            float val = oacc[dt][i] / lrun[i];
            O[(size_t)(b * Nq + qrow0 + quad * 4 + i) * D_ + h * DH + dt * 16 + ln16] = val;
        }
}

// ---------------------------------------------------------------------------
extern "C" void kernel_launch(void* const* d_in, const int* in_sizes, int n_in,
                              void* d_out, int out_size, void* d_ws, size_t ws_size,
                              hipStream_t stream)
{
    (void)in_sizes; (void)n_in; (void)out_size; (void)ws_size;
    const float* x      = (const float*)d_in[0];
    const float* cross  = (const float*)d_in[1];
    const float* ca_wq  = (const float*)d_in[2];
    const float* ca_bq  = (const float*)d_in[3];
    const float* ca_wk  = (const float*)d_in[4];
    const float* ca_bk  = (const float*)d_in[5];
    const float* ca_wv  = (const float*)d_in[6];
    const float* ca_bv  = (const float*)d_in[7];
    const float* ca_wo  = (const float*)d_in[8];
    const float* ca_bo  = (const float*)d_in[9];
    const float* sa_wq  = (const float*)d_in[10];
    const float* sa_bq  = (const float*)d_in[11];
    const float* sa_wk  = (const float*)d_in[12];
    const float* sa_bk  = (const float*)d_in[13];
    const float* sa_wv  = (const float*)d_in[14];
    const float* sa_bv  = (const float*)d_in[15];
    const float* sa_wo  = (const float*)d_in[16];
    const float* sa_bo  = (const float*)d_in[17];
    const float* ln1_g  = (const float*)d_in[18];
    const float* ln1_b  = (const float*)d_in[19];
    const float* ln2_g  = (const float*)d_in[20];
    const float* ln2_b  = (const float*)d_in[21];
    const float* mlp_w1 = (const float*)d_in[22];
    const float* mlp_b1 = (const float*)d_in[23];
    const float* mlp_w2 = (const float*)d_in[24];
    const float* mlp_b2 = (const float*)d_in[25];
    float* out = (float*)d_out;

    // workspace layout (floats); total ~111 MiB
    float* ws  = (float*)d_ws;
    float* Q1  = ws;                  // 2*2048*512
    float* K1  = Q1 + 2097152;        // 2*4096*512
    float* V1  = K1 + 4194304;        // 2*4096*512
    float* CTX = V1 + 4194304;        // 2*2048*512
    float* XC  = CTX + 2097152;
    float* XN  = XC + 2097152;
    float* Yb  = XN + 2097152;
    float* H1  = Yb + 2097152;        // 2*2048*2048
    f16* WT    = (f16*)(H1 + 8388608);
    f16* t_caq = WT;
    f16* t_cak = t_caq + 262144;
    f16* t_cav = t_cak + 262144;
    f16* t_cao = t_cav + 262144;
    f16* t_saq = t_cao + 262144;
    f16* t_sak = t_saq + 262144;
    f16* t_sav = t_sak + 262144;
    f16* t_sao = t_sav + 262144;
    f16* t_w1  = t_sao + 262144;      // 512*2048
    f16* t_w2  = t_w1 + 1048576;      // 2048*512

    dim3 tb(32, 8);
    transpose_cvt<<<dim3(16, 16), tb, 0, stream>>>(ca_wq, t_caq, 512, 512);
    transpose_cvt<<<dim3(16, 16), tb, 0, stream>>>(ca_wk, t_cak, 512, 512);
    transpose_cvt<<<dim3(16, 16), tb, 0, stream>>>(ca_wv, t_cav, 512, 512);
    transpose_cvt<<<dim3(16, 16), tb, 0, stream>>>(ca_wo, t_cao, 512, 512);
    transpose_cvt<<<dim3(16, 16), tb, 0, stream>>>(sa_wq, t_saq, 512, 512);
    transpose_cvt<<<dim3(16, 16), tb, 0, stream>>>(sa_wk, t_sak, 512, 512);
    transpose_cvt<<<dim3(16, 16), tb, 0, stream>>>(sa_wv, t_sav, 512, 512);
    transpose_cvt<<<dim3(16, 16), tb, 0, stream>>>(sa_wo, t_sao, 512, 512);
    transpose_cvt<<<dim3(64, 16), tb, 0, stream>>>(mlp_w1, t_w1, 512, 2048);
    transpose_cvt<<<dim3(16, 64), tb, 0, stream>>>(mlp_w2, t_w2, 2048, 512);

    // a) cross-attention
    gemm_kernel<<<dim3(4, 32), 256, 0, stream>>>(x,     t_caq, ca_bq, nullptr, Q1, 4096, 512, 512, 0);
    gemm_kernel<<<dim3(4, 64), 256, 0, stream>>>(cross, t_cak, ca_bk, nullptr, K1, 8192, 512, 512, 0);
    gemm_kernel<<<dim3(4, 64), 256, 0, stream>>>(cross, t_cav, ca_bv, nullptr, V1, 8192, 512, 512, 0);
    attention_kernel<<<dim3(32, 8, 2), 256, 0, stream>>>(Q1, K1, V1, CTX, 2048, 4096);
    gemm_kernel<<<dim3(4, 32), 256, 0, stream>>>(CTX, t_cao, ca_bo, nullptr, XC, 4096, 512, 512, 0);
    // b,c) LN1 + self-attention
    layernorm_kernel<<<4096, 128, 0, stream>>>(XC, ln1_g, ln1_b, XN);
    gemm_kernel<<<dim3(4, 32), 256, 0, stream>>>(XN, t_saq, sa_bq, nullptr, Q1, 4096, 512, 512, 0);
    gemm_kernel<<<dim3(4, 32), 256, 0, stream>>>(XN, t_sak, sa_bk, nullptr, K1, 4096, 512, 512, 0);
    gemm_kernel<<<dim3(4, 32), 256, 0, stream>>>(XN, t_sav, sa_bv, nullptr, V1, 4096, 512, 512, 0);
    attention_kernel<<<dim3(32, 8, 2), 256, 0, stream>>>(Q1, K1, V1, CTX, 2048, 2048);
    // d) y = xc + xs (residual fused into out-proj epilogue)
    gemm_kernel<<<dim3(4, 32), 256, 0, stream>>>(CTX, t_sao, sa_bo, XC, Yb, 4096, 512, 512, 0);
    // e,f) LN2 + GELU MLP
    layernorm_kernel<<<4096, 128, 0, stream>>>(Yb, ln2_g, ln2_b, XN);
    gemm_kernel<<<dim3(16, 32), 256, 0, stream>>>(XN, t_w1, mlp_b1, nullptr, H1, 4096, 2048, 512, 1);
    // g) out = y + h1 @ w2 + b2 (residual fused)
    gemm_kernel<<<dim3(4, 32), 256, 0, stream>>>(H1, t_w2, mlp_b2, Yb, out, 4096, 512, 2048, 0);
}

// Round 2
// 496.923 us; speedup vs baseline: 1.4132x; 1.4132x over previous
//
#include <hip/hip_runtime.h>
#include <math.h>

typedef _Float16 f16;
typedef __attribute__((ext_vector_type(8))) _Float16 f16x8;
typedef __attribute__((ext_vector_type(4))) _Float16 f16x4;
typedef __attribute__((ext_vector_type(4))) float f32x4;

__device__ __forceinline__ void gl_lds16(const f16* g, f16* l) {
    __builtin_amdgcn_global_load_lds((const __attribute__((address_space(1))) void*)g,
                                     (__attribute__((address_space(3))) void*)l, 16, 0, 0);
}

__device__ __forceinline__ f16x8 cvt8(f32x4 a, f32x4 b) {
    f16x8 r;
    r[0] = (f16)a[0]; r[1] = (f16)a[1]; r[2] = (f16)a[2]; r[3] = (f16)a[3];
    r[4] = (f16)b[0]; r[5] = (f16)b[1]; r[6] = (f16)b[2]; r[7] = (f16)b[3];
    return r;
}

// ---------------------------------------------------------------------------
// fp32 -> f16 elementwise (4 elems/thread)
// ---------------------------------------------------------------------------
__global__ __launch_bounds__(256)
void cvt_f16_kernel(const float* __restrict__ X, f16* __restrict__ Y) {
    size_t i = ((size_t)blockIdx.x * 256 + threadIdx.x) * 4;
    f32x4 v = *(const f32x4*)(X + i);
    f16x4 o;
    o[0] = (f16)v[0]; o[1] = (f16)v[1]; o[2] = (f16)v[2]; o[3] = (f16)v[3];
    *(f16x4*)(Y + i) = o;
}

// ---------------------------------------------------------------------------
// Weight transpose + cvt: Wt[n][k] = W[k][n].  block (32,8).
// ---------------------------------------------------------------------------
__global__ __launch_bounds__(256)
void transpose_cvt(const float* __restrict__ W, f16* __restrict__ Wt, int K, int N) {
    __shared__ float t[32][33];
    int tx = threadIdx.x, ty = threadIdx.y;
    int n0 = blockIdx.x * 32, k0 = blockIdx.y * 32;
#pragma unroll
    for (int i = 0; i < 4; i++)
        t[ty + i * 8][tx] = W[(size_t)(k0 + ty + i * 8) * N + n0 + tx];
    __syncthreads();
#pragma unroll
    for (int i = 0; i < 4; i++)
        Wt[(size_t)(n0 + ty + i * 8) * K + k0 + tx] = (f16)t[tx][ty + i * 8];
}

struct P8 { const float* s[8]; f16* d[8]; };
__global__ __launch_bounds__(256)
void transpose_cvt8(P8 p) {
    __shared__ float t[32][33];
    const float* W = p.s[blockIdx.z];
    f16* Wt = p.d[blockIdx.z];
    int tx = threadIdx.x, ty = threadIdx.y;
    int n0 = blockIdx.x * 32, k0 = blockIdx.y * 32;
#pragma unroll
    for (int i = 0; i < 4; i++)
        t[ty + i * 8][tx] = W[(size_t)(k0 + ty + i * 8) * 512 + n0 + tx];
    __syncthreads();
#pragma unroll
    for (int i = 0; i < 4; i++)
        Wt[(size_t)(n0 + ty + i * 8) * 512 + k0 + tx] = (f16)t[tx][ty + i * 8];
}

// ---------------------------------------------------------------------------
// V head-major [bh][Nk][64] -> transposed [bh][64][Nk] (f16)
// grid (Nk/64, 16), block 256
// ---------------------------------------------------------------------------
__global__ __launch_bounds__(256)
void transpose_v(const f16* __restrict__ Vh, f16* __restrict__ Vt, int Nk) {
    __shared__ f16 t[64][72];
    int bh = blockIdx.y, k0 = blockIdx.x * 64;
    int tid = threadIdx.x;
    int kr = tid >> 2, dc = (tid & 3) * 16;
    const f16* src = Vh + ((size_t)bh * Nk + k0 + kr) * 64 + dc;
    f16x8 a = *(const f16x8*)src;
    f16x8 b = *(const f16x8*)(src + 8);
    *(f16x8*)&t[kr][dc] = a;
    *(f16x8*)&t[kr][dc + 8] = b;
    __syncthreads();
    int dr = tid >> 2, kc = (tid & 3) * 16;
    f16x8 o0, o1;
#pragma unroll
    for (int j = 0; j < 8; j++) { o0[j] = t[kc + j][dr]; o1[j] = t[kc + 8 + j][dr]; }
    f16* dst = Vt + ((size_t)bh * 64 + dr) * Nk + k0 + kc;
    *(f16x8*)dst = o0;
    *(f16x8*)(dst + 8) = o1;
}

// ---------------------------------------------------------------------------
// LayerNorm over D=512, f32 in -> f16 out. 1 block (128 thr) per row.
// ---------------------------------------------------------------------------
__global__ __launch_bounds__(128)
void layernorm_f16(const float* __restrict__ X, const float* __restrict__ g,
                   const float* __restrict__ bta, f16* __restrict__ Y)
{
    __shared__ float red[4];
    int row = blockIdx.x;
    int tid = threadIdx.x;
    const float* x = X + (size_t)row * 512;
    f32x4 v = *(const f32x4*)(x + tid * 4);
    float s  = v[0] + v[1] + v[2] + v[3];
    float ss = v[0] * v[0] + v[1] * v[1] + v[2] * v[2] + v[3] * v[3];
#pragma unroll
    for (int m = 1; m < 64; m <<= 1) {
        s  += __shfl_xor(s, m, 64);
        ss += __shfl_xor(ss, m, 64);
    }
    int wave = tid >> 6, lane = tid & 63;
    if (lane == 0) { red[wave * 2] = s; red[wave * 2 + 1] = ss; }
    __syncthreads();
    s = red[0] + red[2]; ss = red[1] + red[3];
    float mu  = s * (1.0f / 512);
    float var = ss * (1.0f / 512) - mu * mu;
    float inv = rsqrtf(var + 1e-5f);
    f32x4 gv = *(const f32x4*)(g + tid * 4);
    f32x4 bv = *(const f32x4*)(bta + tid * 4);
    f16x4 o;
#pragma unroll
    for (int i = 0; i < 4; i++) o[i] = (f16)((v[i] - mu) * inv * gv[i] + bv[i]);
    *(f16x4*)(Y + (size_t)row * 512 + tid * 4) = o;
}

// ---------------------------------------------------------------------------
// GEMM f16: C = A[M][K] @ W[K][N] (+bias, +res, gelu), Wt = W^T [N][K].
// 128x128 tile, BK=32, 256 thr, global_load_lds width-16 staging.
// Epilogue can write f32 row-major, f16 row-major, and/or f16 head-major
// (Q/K/V split by 512-col segment).
// ---------------------------------------------------------------------------
__global__ __launch_bounds__(256)
void gemm_f16(const f16* __restrict__ A, const f16* __restrict__ Wt,
              const float* __restrict__ b0, const float* __restrict__ b1,
              const float* __restrict__ b2, const float* __restrict__ res,
              float* __restrict__ Cf32, f16* __restrict__ C16,
              f16* __restrict__ hm0, f16* __restrict__ hm1, f16* __restrict__ hm2,
              int M, int N, int K, int NBshift, int fused, int act)
{
    __shared__ __align__(16) f16 As[128 * 32];
    __shared__ __align__(16) f16 Bs[128 * 32];
    int tid = threadIdx.x, lane = tid & 63, wave = tid >> 6;
    int quad = lane >> 4, ln16 = lane & 15;
    int wm = wave >> 1, wn = wave & 1;
    int bm0 = blockIdx.y * 128, bn0 = blockIdx.x * 128;

    f32x4 acc[4][4];
#pragma unroll
    for (int i = 0; i < 4; i++)
#pragma unroll
        for (int j = 0; j < 4; j++) acc[i][j] = (f32x4){0.f, 0.f, 0.f, 0.f};

    // chunk L in [0,512): row r=L>>2, cc=L&3 ; thread handles L=tid, tid+256
    int r0 = tid >> 2, cc0 = tid & 3;
    const f16* aG0 = A  + (size_t)(bm0 + r0) * K + cc0 * 8;
    const f16* aG1 = aG0 + (size_t)64 * K;
    const f16* bG0 = Wt + (size_t)(bn0 + r0) * K + cc0 * 8;
    const f16* bG1 = bG0 + (size_t)64 * K;
    f16* al0 = As + tid * 8;
    f16* al1 = As + (tid + 256) * 8;
    f16* bl0 = Bs + tid * 8;
    f16* bl1 = Bs + (tid + 256) * 8;

    for (int kt = 0; kt < K; kt += 32) {
        __syncthreads();
        gl_lds16(aG0, al0); gl_lds16(aG1, al1);
        gl_lds16(bG0, bl0); gl_lds16(bG1, bl1);
        __syncthreads();
        f16x8 af[4], bf[4];
#pragma unroll
        for (int mt = 0; mt < 4; mt++)
            af[mt] = *(const f16x8*)&As[(wm * 64 + mt * 16 + ln16) * 32 + quad * 8];
#pragma unroll
        for (int nt = 0; nt < 4; nt++)
            bf[nt] = *(const f16x8*)&Bs[(wn * 64 + nt * 16 + ln16) * 32 + quad * 8];
#pragma unroll
        for (int mt = 0; mt < 4; mt++)
#pragma unroll
            for (int nt = 0; nt < 4; nt++)
                acc[mt][nt] = __builtin_amdgcn_mfma_f32_16x16x32_f16(af[mt], bf[nt], acc[mt][nt], 0, 0, 0);
        aG0 += 32; aG1 += 32; bG0 += 32; bG1 += 32;
    }

    int NB = 1 << NBshift;
#pragma unroll
    for (int mt = 0; mt < 4; mt++) {
#pragma unroll
        for (int nt = 0; nt < 4; nt++) {
            int row = bm0 + wm * 64 + mt * 16 + quad * 4;
            int col = bn0 + wn * 64 + nt * 16 + ln16;
            float bv;
            if (fused) {
                int seg = col >> 9;
                const float* bp = seg == 0 ? b0 : (seg == 1 ? b1 : b2);
                bv = bp[col & 511];
            } else bv = b0[col];
#pragma unroll
            for (int i = 0; i < 4; i++) {
                int r = row + i;
                float v = acc[mt][nt][i] + bv;
                size_t idx = (size_t)r * N + col;
                if (res) v += res[idx];
                if (act) v = 0.5f * v * (1.0f + erff(v * 0.70710678118654752f));
                if (Cf32) Cf32[idx] = v;
                if (C16) C16[idx] = (f16)v;
                if (hm0) {
                    int seg = col >> 9;
                    f16* hp = seg == 0 ? hm0 : (seg == 1 ? hm1 : hm2);
                    int hh = (col >> 6) & 7, d = col & 63;
                    int bt = r >> NBshift, rr = r & (NB - 1);
                    hp[(((size_t)bt * 8 + hh) * NB + rr) * 64 + d] = (f16)v;
                }
            }
        }
    }
}

// ---------------------------------------------------------------------------
// Flash attention, f16 inputs.
// Qh,Kh: [bh][N][64] head-major; Vt: [bh][64][Nk] transposed; O: f16 [B*Nq][512].
// grid (Nq/64, H, B), 256 thr (4 waves x 16 q-rows). KT=128 key tile.
// LDS tiles filled via global_load_lds with XOR-swizzled 16B chunks.
// Row-sum via ones-column MFMA on P (no sum shuffles, no cross-lane div).
// ---------------------------------------------------------------------------
__global__ __launch_bounds__(256)
void attention_f16(const f16* __restrict__ Qh, const f16* __restrict__ Kh,
                   const f16* __restrict__ Vt, f16* __restrict__ O,
                   int Nq, int Nk)
{
    __shared__ __align__(16) f16 Kt[128 * 64];
    __shared__ __align__(16) f16 Vs[64 * 128];
    __shared__ __align__(16) f16 Ps[4][16 * 136];
    int b = blockIdx.z, h = blockIdx.y, bh = b * 8 + h;
    int tid = threadIdx.x, lane = tid & 63, wave = tid >> 6;
    int quad = lane >> 4, ln16 = lane & 15;
    int qrow0 = blockIdx.x * 64 + wave * 16;

    // Q fragments (A-layout), fold in 1/8 scale (exact pow2)
    f16x8 aq0, aq1;
    {
        const f16* qp = Qh + ((size_t)bh * Nq + qrow0 + ln16) * 64 + quad * 8;
        aq0 = *(const f16x8*)qp;
        aq1 = *(const f16x8*)(qp + 32);
        const f16 sc = (f16)0.125f;
#pragma unroll
        for (int j = 0; j < 8; j++) { aq0[j] *= sc; aq1[j] *= sc; }
    }
    f16x8 ones;
#pragma unroll
    for (int j = 0; j < 8; j++) ones[j] = (f16)1.0f;

    float mrun[4];
    f32x4 oacc[4], aol = (f32x4){0.f, 0.f, 0.f, 0.f};
#pragma unroll
    for (int i = 0; i < 4; i++) { mrun[i] = -INFINITY; oacc[i] = (f32x4){0.f, 0.f, 0.f, 0.f}; }

    const f16* kbase = Kh + (size_t)bh * Nk * 64;
    const f16* vbase = Vt + (size_t)bh * 64 * Nk;

    // staging chunk maps (4 K-chunks + 4 V-chunks per thread)
    const f16* kg[4]; f16* kl[4];
    const f16* vg[4]; f16* vl[4];
#pragma unroll
    for (int j = 0; j < 4; j++) {
        int LK = tid + j * 256;
        int rK = LK >> 3, cK = (LK & 7) ^ (rK & 7);
        kg[j] = kbase + (size_t)rK * 64 + cK * 8;
        kl[j] = Kt + (size_t)LK * 8;
        int LV = tid + j * 256;
        int dV = LV >> 4, cV = LV & 15;
        int cS = (cV & 8) | ((cV & 7) ^ (dV & 7));
        vg[j] = vbase + (size_t)dV * Nk + cS * 8;
        vl[j] = Vs + (size_t)LV * 8;
    }

    for (int k0 = 0; k0 < Nk; k0 += 128) {
        __syncthreads();
#pragma unroll
        for (int j = 0; j < 4; j++) gl_lds16(kg[j] + (size_t)k0 * 64, kl[j]);
#pragma unroll
        for (int j = 0; j < 4; j++) gl_lds16(vg[j] + k0, vl[j]);
        __syncthreads();

        // S = Q K^T (pre-scaled)
        f32x4 s[8];
#pragma unroll
        for (int nt = 0; nt < 8; nt++) {
            int key = nt * 16 + ln16;
            int c0 = quad ^ (key & 7);
            int c1 = (4 + quad) ^ (key & 7);
            f16x8 kb0 = *(const f16x8*)&Kt[key * 64 + c0 * 8];
            f16x8 kb1 = *(const f16x8*)&Kt[key * 64 + c1 * 8];
            f32x4 z = (f32x4){0.f, 0.f, 0.f, 0.f};
            z = __builtin_amdgcn_mfma_f32_16x16x32_f16(aq0, kb0, z, 0, 0, 0);
            z = __builtin_amdgcn_mfma_f32_16x16x32_f16(aq1, kb1, z, 0, 0, 0);
            s[nt] = z;
        }
        // row max (butterfly over the 16 lanes holding the row)
        float mx[4];
#pragma unroll
        for (int i = 0; i < 4; i++) {
            float a = fmaxf(fmaxf(s[0][i], s[1][i]), fmaxf(s[2][i], s[3][i]));
            float c = fmaxf(fmaxf(s[4][i], s[5][i]), fmaxf(s[6][i], s[7][i]));
            mx[i] = fmaxf(a, c);
        }
#pragma unroll
        for (int m = 1; m < 16; m <<= 1)
#pragma unroll
            for (int i = 0; i < 4; i++) mx[i] = fmaxf(mx[i], __shfl_xor(mx[i], m, 64));
        float alpha[4];
#pragma unroll
        for (int i = 0; i < 4; i++) {
            float mn = fmaxf(mrun[i], mx[i]);
            alpha[i] = __expf(mrun[i] - mn);
            mrun[i] = mn;
        }
        // P = exp(S - m) -> per-wave LDS (C-layout -> A-layout)
        f16* pw = &Ps[wave][0];
#pragma unroll
        for (int nt = 0; nt < 8; nt++)
#pragma unroll
            for (int i = 0; i < 4; i++)
                pw[(quad * 4 + i) * 136 + nt * 16 + ln16] = (f16)__expf(s[nt][i] - mrun[i]);
        // rescale running state
#pragma unroll
        for (int dt = 0; dt < 4; dt++)
#pragma unroll
            for (int i = 0; i < 4; i++) oacc[dt][i] *= alpha[i];
#pragma unroll
        for (int i = 0; i < 4; i++) aol[i] *= alpha[i];

        f16x8 ap[4];
#pragma unroll
        for (int kk = 0; kk < 4; kk++)
            ap[kk] = *(const f16x8*)&pw[ln16 * 136 + kk * 32 + quad * 8];
        // l += P @ ones  (row-sum lands in same lane layout as oacc)
#pragma unroll
        for (int kk = 0; kk < 4; kk++)
            aol = __builtin_amdgcn_mfma_f32_16x16x32_f16(ap[kk], ones, aol, 0, 0, 0);
        // O += P @ V
#pragma unroll
        for (int dt = 0; dt < 4; dt++) {
            int d = dt * 16 + ln16;
#pragma unroll
            for (int kk = 0; kk < 4; kk++) {
                int cc = kk * 4 + quad;
                int cS = (cc & 8) | ((cc & 7) ^ (d & 7));
                f16x8 vb = *(const f16x8*)&Vs[d * 128 + cS * 8];
                oacc[dt] = __builtin_amdgcn_mfma_f32_16x16x32_f16(ap[kk], vb, oacc[dt], 0, 0, 0);
            }
        }
    }

#pragma unroll
    for (int dt = 0; dt < 4; dt++)
#pragma unroll
        for (int i = 0; i < 4; i++) {
            float val = oacc[dt][i] / aol[i];
            O[((size_t)b * Nq + qrow0 + quad * 4 + i) * 512 + h * 64 + dt * 16 + ln16] = (f16)val;
        }
}

// ---------------------------------------------------------------------------
extern "C" void kernel_launch(void* const* d_in, const int* in_sizes, int n_in,
                              void* d_out, int out_size, void* d_ws, size_t ws_size,
                              hipStream_t stream)
{
    (void)in_sizes; (void)n_in; (void)out_size; (void)ws_size;
    const float* x      = (const float*)d_in[0];
    const float* cross  = (const float*)d_in[1];
    const float* ca_wq  = (const float*)d_in[2];
    const float* ca_bq  = (const float*)d_in[3];
    const float* ca_wk  = (const float*)d_in[4];
    const float* ca_bk  = (const float*)d_in[5];
    const float* ca_wv  = (const float*)d_in[6];
    const float* ca_bv  = (const float*)d_in[7];
    const float* ca_wo  = (const float*)d_in[8];
    const float* ca_bo  = (const float*)d_in[9];
    const float* sa_wq  = (const float*)d_in[10];
    const float* sa_bq  = (const float*)d_in[11];
    const float* sa_wk  = (const float*)d_in[12];
    const float* sa_bk  = (const float*)d_in[13];
    const float* sa_wv  = (const float*)d_in[14];
    const float* sa_bv  = (const float*)d_in[15];
    const float* sa_wo  = (const float*)d_in[16];
    const float* sa_bo  = (const float*)d_in[17];
    const float* ln1_g  = (const float*)d_in[18];
    const float* ln1_b  = (const float*)d_in[19];
    const float* ln2_g  = (const float*)d_in[20];
    const float* ln2_b  = (const float*)d_in[21];
    const float* mlp_w1 = (const float*)d_in[22];
    const float* mlp_b1 = (const float*)d_in[23];
    const float* mlp_w2 = (const float*)d_in[24];
    const float* mlp_b2 = (const float*)d_in[25];
    float* out = (float*)d_out;

    // ---- workspace layout ----
    float* XC = (float*)d_ws;            // 2M f32
    float* Yb = XC + 2097152;            // 2M f32
    f16* fb   = (f16*)(Yb + 2097152);
    f16* xh     = fb;                    // 2M
    f16* crossh = xh + 2097152;          // 4M
    f16* xnh    = crossh + 4194304;      // 2M
    f16* xn2h   = xnh + 2097152;         // 2M
    f16* Qh     = xn2h + 2097152;        // 2M
    f16* Kh     = Qh + 2097152;          // 4M
    f16* Vh     = Kh + 4194304;          // 4M
    f16* Vtb    = Vh + 4194304;          // 4M
    f16* ctxh   = Vtb + 4194304;         // 2M
    f16* h1h    = ctxh + 2097152;        // 8M
    f16* t_caq  = h1h + 8388608;         // 8 x 256K square weights
    f16* t_cak  = t_caq + 262144;
    f16* t_cav  = t_cak + 262144;
    f16* t_cao  = t_cav + 262144;
    f16* t_saq  = t_cao + 262144;
    f16* t_sak  = t_saq + 262144;
    f16* t_sav  = t_sak + 262144;
    f16* t_sao  = t_sav + 262144;
    f16* t_w1   = t_sao + 262144;        // 1M  [2048][512]
    f16* t_w2   = t_w1 + 1048576;        // 1M  [512][2048]

    dim3 tb(32, 8);
    P8 p8;
    p8.s[0] = ca_wq; p8.d[0] = t_caq;
    p8.s[1] = ca_wk; p8.d[1] = t_cak;
    p8.s[2] = ca_wv; p8.d[2] = t_cav;
    p8.s[3] = ca_wo; p8.d[3] = t_cao;
    p8.s[4] = sa_wq; p8.d[4] = t_saq;
    p8.s[5] = sa_wk; p8.d[5] = t_sak;
    p8.s[6] = sa_wv; p8.d[6] = t_sav;
    p8.s[7] = sa_wo; p8.d[7] = t_sao;
    transpose_cvt8<<<dim3(16, 16, 8), tb, 0, stream>>>(p8);
    transpose_cvt<<<dim3(64, 16), tb, 0, stream>>>(mlp_w1, t_w1, 512, 2048);
    transpose_cvt<<<dim3(16, 64), tb, 0, stream>>>(mlp_w2, t_w2, 2048, 512);
    cvt_f16_kernel<<<2048, 256, 0, stream>>>(x, xh);
    cvt_f16_kernel<<<4096, 256, 0, stream>>>(cross, crossh);

    // a) cross-attention
    gemm_f16<<<dim3(4, 32), 256, 0, stream>>>(xh, t_caq, ca_bq, nullptr, nullptr, nullptr,
        nullptr, nullptr, Qh, nullptr, nullptr, 4096, 512, 512, 11, 0, 0);
    gemm_f16<<<dim3(8, 64), 256, 0, stream>>>(crossh, t_cak, ca_bk, ca_bv, nullptr, nullptr,
        nullptr, nullptr, Kh, Vh, nullptr, 8192, 1024, 512, 12, 1, 0);
    transpose_v<<<dim3(64, 16), 256, 0, stream>>>(Vh, Vtb, 4096);
    attention_f16<<<dim3(32, 8, 2), 256, 0, stream>>>(Qh, Kh, Vtb, ctxh, 2048, 4096);
    gemm_f16<<<dim3(4, 32), 256, 0, stream>>>(ctxh, t_cao, ca_bo, nullptr, nullptr, nullptr,
        XC, nullptr, nullptr, nullptr, nullptr, 4096, 512, 512, 11, 0, 0);
    // b,c) LN1 + self-attention (fused QKV)
    layernorm_f16<<<4096, 128, 0, stream>>>(XC, ln1_g, ln1_b, xnh);
    gemm_f16<<<dim3(12, 32), 256, 0, stream>>>(xnh, t_saq, sa_bq, sa_bk, sa_bv, nullptr,
        nullptr, nullptr, Qh, Kh, Vh, 4096, 1536, 512, 11, 1, 0);
    transpose_v<<<dim3(32, 16), 256, 0, stream>>>(Vh, Vtb, 2048);
    attention_f16<<<dim3(32, 8, 2), 256, 0, stream>>>(Qh, Kh, Vtb, ctxh, 2048, 2048);
    // d) y = xc + xs
    gemm_f16<<<dim3(4, 32), 256, 0, stream>>>(ctxh, t_sao, sa_bo, nullptr, nullptr, XC,
        Yb, nullptr, nullptr, nullptr, nullptr, 4096, 512, 512, 11, 0, 0);
    // e,f) LN2 + GELU MLP
    layernorm_f16<<<4096, 128, 0, stream>>>(Yb, ln2_g, ln2_b, xn2h);
    gemm_f16<<<dim3(16, 32), 256, 0, stream>>>(xn2h, t_w1, mlp_b1, nullptr, nullptr, nullptr,
        nullptr, h1h, nullptr, nullptr, nullptr, 4096, 2048, 512, 11, 0, 1);
    // g) out = y + h1 @ w2 + b2
    gemm_f16<<<dim3(4, 32), 256, 0, stream>>>(h1h, t_w2, mlp_b2, nullptr, nullptr, Yb,
        out, nullptr, nullptr, nullptr, nullptr, 4096, 512, 2048, 11, 0, 0);
}

// Round 3
// 433.091 us; speedup vs baseline: 1.6215x; 1.1474x over previous
//
#include <hip/hip_runtime.h>
#include <math.h>

typedef _Float16 f16;
typedef __attribute__((ext_vector_type(8))) _Float16 f16x8;
typedef __attribute__((ext_vector_type(4))) _Float16 f16x4;
typedef __attribute__((ext_vector_type(4))) float f32x4;

#define QSCALE 0.1803368801111204f  /* 0.125 * log2(e) */

__device__ __forceinline__ void gl_lds16(const f16* g, f16* l) {
    __builtin_amdgcn_global_load_lds((const __attribute__((address_space(1))) void*)g,
                                     (__attribute__((address_space(3))) void*)l, 16, 0, 0);
}

// ---------------------------------------------------------------------------
// fp32 -> f16 elementwise
// ---------------------------------------------------------------------------
__global__ __launch_bounds__(256)
void cvt_f16_kernel(const float* __restrict__ X, f16* __restrict__ Y) {
    size_t i = ((size_t)blockIdx.x * 256 + threadIdx.x) * 4;
    f32x4 v = *(const f32x4*)(X + i);
    f16x4 o;
    o[0] = (f16)v[0]; o[1] = (f16)v[1]; o[2] = (f16)v[2]; o[3] = (f16)v[3];
    *(f16x4*)(Y + i) = o;
}

// ---------------------------------------------------------------------------
// Weight transpose + cvt: Wt[n][k] = W[k][n].  block (32,8).
// ---------------------------------------------------------------------------
__global__ __launch_bounds__(256)
void transpose_cvt(const float* __restrict__ W, f16* __restrict__ Wt, int K, int N) {
    __shared__ float t[32][33];
    int tx = threadIdx.x, ty = threadIdx.y;
    int n0 = blockIdx.x * 32, k0 = blockIdx.y * 32;
#pragma unroll
    for (int i = 0; i < 4; i++)
        t[ty + i * 8][tx] = W[(size_t)(k0 + ty + i * 8) * N + n0 + tx];
    __syncthreads();
#pragma unroll
    for (int i = 0; i < 4; i++)
        Wt[(size_t)(n0 + ty + i * 8) * K + k0 + tx] = (f16)t[tx][ty + i * 8];
}

struct P8 { const float* s[8]; f16* d[8]; };
__global__ __launch_bounds__(256)
void transpose_cvt8(P8 p) {
    __shared__ float t[32][33];
    const float* W = p.s[blockIdx.z];
    f16* Wt = p.d[blockIdx.z];
    int tx = threadIdx.x, ty = threadIdx.y;
    int n0 = blockIdx.x * 32, k0 = blockIdx.y * 32;
#pragma unroll
    for (int i = 0; i < 4; i++)
        t[ty + i * 8][tx] = W[(size_t)(k0 + ty + i * 8) * 512 + n0 + tx];
    __syncthreads();
#pragma unroll
    for (int i = 0; i < 4; i++)
        Wt[(size_t)(n0 + ty + i * 8) * 512 + k0 + tx] = (f16)t[tx][ty + i * 8];
}

// ---------------------------------------------------------------------------
// V head-major [bh][Nk][64] -> [bh][64][Nk] (f16).  grid (Nk/64, 16)
// ---------------------------------------------------------------------------
__global__ __launch_bounds__(256)
void transpose_v(const f16* __restrict__ Vh, f16* __restrict__ Vt, int Nk) {
    __shared__ f16 t[64][72];
    int bh = blockIdx.y, k0 = blockIdx.x * 64;
    int tid = threadIdx.x;
    int kr = tid >> 2, dc = (tid & 3) * 16;
    const f16* src = Vh + ((size_t)bh * Nk + k0 + kr) * 64 + dc;
    f16x8 a = *(const f16x8*)src;
    f16x8 b = *(const f16x8*)(src + 8);
    *(f16x8*)&t[kr][dc] = a;
    *(f16x8*)&t[kr][dc + 8] = b;
    __syncthreads();
    int dr = tid >> 2, kc = (tid & 3) * 16;
    f16x8 o0, o1;
#pragma unroll
    for (int j = 0; j < 8; j++) { o0[j] = t[kc + j][dr]; o1[j] = t[kc + 8 + j][dr]; }
    f16* dst = Vt + ((size_t)bh * 64 + dr) * Nk + k0 + kc;
    *(f16x8*)dst = o0;
    *(f16x8*)(dst + 8) = o1;
}

// ---------------------------------------------------------------------------
// LayerNorm D=512, f32 in -> f16 out. 1 block (128 thr) per row.
// ---------------------------------------------------------------------------
__global__ __launch_bounds__(128)
void layernorm_f16(const float* __restrict__ X, const float* __restrict__ g,
                   const float* __restrict__ bta, f16* __restrict__ Y)
{
    __shared__ float red[4];
    int row = blockIdx.x;
    int tid = threadIdx.x;
    const float* x = X + (size_t)row * 512;
    f32x4 v = *(const f32x4*)(x + tid * 4);
    float s  = v[0] + v[1] + v[2] + v[3];
    float ss = v[0] * v[0] + v[1] * v[1] + v[2] * v[2] + v[3] * v[3];
#pragma unroll
    for (int m = 1; m < 64; m <<= 1) {
        s  += __shfl_xor(s, m, 64);
        ss += __shfl_xor(ss, m, 64);
    }
    int wave = tid >> 6, lane = tid & 63;
    if (lane == 0) { red[wave * 2] = s; red[wave * 2 + 1] = ss; }
    __syncthreads();
    s = red[0] + red[2]; ss = red[1] + red[3];
    float mu  = s * (1.0f / 512);
    float var = ss * (1.0f / 512) - mu * mu;
    float inv = rsqrtf(var + 1e-5f);
    f32x4 gv = *(const f32x4*)(g + tid * 4);
    f32x4 bv = *(const f32x4*)(bta + tid * 4);
    f16x4 o;
#pragma unroll
    for (int i = 0; i < 4; i++) o[i] = (f16)((v[i] - mu) * inv * gv[i] + bv[i]);
    *(f16x4*)(Y + (size_t)row * 512 + tid * 4) = o;
}

// ---------------------------------------------------------------------------
// GEMM 128x128 tile, BK=64, XOR-swizzled LDS rows, global_load_lds staging.
// Epilogue: f32 / f16 row-major, f16 head-major (multi-segment QKV, seg0
// scaled by s0).
// ---------------------------------------------------------------------------
__global__ __launch_bounds__(256)
void gemm_f16(const f16* __restrict__ A, const f16* __restrict__ Wt,
              const float* __restrict__ b0, const float* __restrict__ b1,
              const float* __restrict__ b2, const float* __restrict__ res,
              float* __restrict__ Cf32, f16* __restrict__ C16,
              f16* __restrict__ hm0, f16* __restrict__ hm1, f16* __restrict__ hm2,
              int N, int K, int NBshift, int fused, int act, float s0)
{
    __shared__ __align__(16) f16 As[128 * 64];
    __shared__ __align__(16) f16 Bs[128 * 64];
    int tid = threadIdx.x, lane = tid & 63, wave = tid >> 6;
    int quad = lane >> 4, ln16 = lane & 15;
    int wm = wave >> 1, wn = wave & 1;
    int bm0 = blockIdx.y * 128, bn0 = blockIdx.x * 128;

    f32x4 acc[4][4];
#pragma unroll
    for (int i = 0; i < 4; i++)
#pragma unroll
        for (int j = 0; j < 4; j++) acc[i][j] = (f32x4){0.f, 0.f, 0.f, 0.f};

    const f16* ag[4]; const f16* bg[4]; f16* al[4]; f16* bl[4];
#pragma unroll
    for (int j = 0; j < 4; j++) {
        int L = tid + j * 256;
        int row = L >> 3, cc = (L & 7) ^ (row & 7);
        ag[j] = A  + (size_t)(bm0 + row) * K + cc * 8;
        bg[j] = Wt + (size_t)(bn0 + row) * K + cc * 8;
        al[j] = As + (size_t)L * 8;
        bl[j] = Bs + (size_t)L * 8;
    }
    int sw0 = (quad ^ (ln16 & 7)) * 8, sw1 = ((4 + quad) ^ (ln16 & 7)) * 8;

    for (int kt = 0; kt < K; kt += 64) {
        __syncthreads();
#pragma unroll
        for (int j = 0; j < 4; j++) gl_lds16(ag[j], al[j]);
#pragma unroll
        for (int j = 0; j < 4; j++) gl_lds16(bg[j], bl[j]);
        __syncthreads();
#pragma unroll
        for (int h = 0; h < 2; h++) {
            int sw = h ? sw1 : sw0;
            f16x8 af[4], bf[4];
#pragma unroll
            for (int mt = 0; mt < 4; mt++)
                af[mt] = *(const f16x8*)&As[(wm * 64 + mt * 16 + ln16) * 64 + sw];
#pragma unroll
            for (int nt = 0; nt < 4; nt++)
                bf[nt] = *(const f16x8*)&Bs[(wn * 64 + nt * 16 + ln16) * 64 + sw];
#pragma unroll
            for (int mt = 0; mt < 4; mt++)
#pragma unroll
                for (int nt = 0; nt < 4; nt++)
                    acc[mt][nt] = __builtin_amdgcn_mfma_f32_16x16x32_f16(af[mt], bf[nt], acc[mt][nt], 0, 0, 0);
        }
#pragma unroll
        for (int j = 0; j < 4; j++) { ag[j] += 64; bg[j] += 64; }
    }

    int NB = 1 << NBshift;
#pragma unroll
    for (int mt = 0; mt < 4; mt++) {
#pragma unroll
        for (int nt = 0; nt < 4; nt++) {
            int row = bm0 + wm * 64 + mt * 16 + quad * 4;
            int col = bn0 + wn * 64 + nt * 16 + ln16;
            float bv;
            if (fused) {
                int seg = col >> 9;
                const float* bp = seg == 0 ? b0 : (seg == 1 ? b1 : b2);
                bv = bp[col & 511];
            } else bv = b0[col];
#pragma unroll
            for (int i = 0; i < 4; i++) {
                int r = row + i;
                float v = acc[mt][nt][i] + bv;
                size_t idx = (size_t)r * N + col;
                if (res) v += res[idx];
                if (act) v = 0.5f * v * (1.0f + erff(v * 0.70710678118654752f));
                if (Cf32) Cf32[idx] = v;
                if (C16) C16[idx] = (f16)v;
                if (hm0) {
                    int seg = col >> 9;
                    f16* hp = seg == 0 ? hm0 : (seg == 1 ? hm1 : hm2);
                    float vv = seg == 0 ? v * s0 : v;
                    int hh = (col >> 6) & 7, d = col & 63;
                    int bt = r >> NBshift, rr = r & (NB - 1);
                    hp[(((size_t)bt * 8 + hh) * NB + rr) * 64 + d] = (f16)vv;
                }
            }
        }
    }
}

// ---------------------------------------------------------------------------
// GEMM 64x64 tile, BK=64, for N=512 shapes (big grids). Same LDS swizzle.
// ---------------------------------------------------------------------------
__global__ __launch_bounds__(256)
void gemm64(const f16* __restrict__ A, const f16* __restrict__ Wt,
            const float* __restrict__ bias, const float* __restrict__ res,
            float* __restrict__ Cf32, f16* __restrict__ hm0,
            int N, int K, int NBshift, float s0)
{
    __shared__ __align__(16) f16 As[64 * 64];
    __shared__ __align__(16) f16 Bs[64 * 64];
    int tid = threadIdx.x, lane = tid & 63, wave = tid >> 6;
    int quad = lane >> 4, ln16 = lane & 15;
    int wm = wave >> 1, wn = wave & 1;
    int bm0 = blockIdx.y * 64, bn0 = blockIdx.x * 64;

    f32x4 acc[2][2];
#pragma unroll
    for (int i = 0; i < 2; i++)
#pragma unroll
        for (int j = 0; j < 2; j++) acc[i][j] = (f32x4){0.f, 0.f, 0.f, 0.f};

    const f16* ag[2]; const f16* bg[2]; f16* al[2]; f16* bl[2];
#pragma unroll
    for (int j = 0; j < 2; j++) {
        int L = tid + j * 256;
        int row = L >> 3, cc = (L & 7) ^ (row & 7);
        ag[j] = A  + (size_t)(bm0 + row) * K + cc * 8;
        bg[j] = Wt + (size_t)(bn0 + row) * K + cc * 8;
        al[j] = As + (size_t)L * 8;
        bl[j] = Bs + (size_t)L * 8;
    }
    int sw0 = (quad ^ (ln16 & 7)) * 8, sw1 = ((4 + quad) ^ (ln16 & 7)) * 8;

    for (int kt = 0; kt < K; kt += 64) {
        __syncthreads();
#pragma unroll
        for (int j = 0; j < 2; j++) gl_lds16(ag[j], al[j]);
#pragma unroll
        for (int j = 0; j < 2; j++) gl_lds16(bg[j], bl[j]);
        __syncthreads();
#pragma unroll
        for (int h = 0; h < 2; h++) {
            int sw = h ? sw1 : sw0;
            f16x8 af[2], bf[2];
#pragma unroll
            for (int mt = 0; mt < 2; mt++)
                af[mt] = *(const f16x8*)&As[(wm * 32 + mt * 16 + ln16) * 64 + sw];
#pragma unroll
            for (int nt = 0; nt < 2; nt++)
                bf[nt] = *(const f16x8*)&Bs[(wn * 32 + nt * 16 + ln16) * 64 + sw];
#pragma unroll
            for (int mt = 0; mt < 2; mt++)
#pragma unroll
                for (int nt = 0; nt < 2; nt++)
                    acc[mt][nt] = __builtin_amdgcn_mfma_f32_16x16x32_f16(af[mt], bf[nt], acc[mt][nt], 0, 0, 0);
        }
#pragma unroll
        for (int j = 0; j < 2; j++) { ag[j] += 64; bg[j] += 64; }
    }

    int NB = 1 << NBshift;
#pragma unroll
    for (int mt = 0; mt < 2; mt++) {
#pragma unroll
        for (int nt = 0; nt < 2; nt++) {
            int row = bm0 + wm * 32 + mt * 16 + quad * 4;
            int col = bn0 + wn * 32 + nt * 16 + ln16;
            float bv = bias[col];
#pragma unroll
            for (int i = 0; i < 4; i++) {
                int r = row + i;
                float v = acc[mt][nt][i] + bv;
                size_t idx = (size_t)r * N + col;
                if (res) v += res[idx];
                if (Cf32) Cf32[idx] = v;
                if (hm0) {
                    int hh = (col >> 6) & 7, d = col & 63;
                    int bt = r >> NBshift, rr = r & (NB - 1);
                    hm0[(((size_t)bt * 8 + hh) * NB + rr) * 64 + d] = (f16)(v * s0);
                }
            }
        }
    }
}

// ---------------------------------------------------------------------------
// Flash attention, key-split x2.  Qh pre-scaled by 0.125*log2e.
// Qh,Kh: [bh][N][64]; Vt: [bh][64][Nk].  Partial out: Op f16
// [sp][bh][2048][64] (unnormalized), ML float2 {m, l} per row (exp2-space).
// grid (Nq/64, 8, B*2), 256 thr.  KT=64.
// ---------------------------------------------------------------------------
__global__ __launch_bounds__(256, 4)
void attention_split(const f16* __restrict__ Qh, const f16* __restrict__ Kh,
                     const f16* __restrict__ Vt, f16* __restrict__ Op,
                     float2* __restrict__ ML, int Nk)
{
    __shared__ __align__(16) f16 Kt[64 * 64];
    __shared__ __align__(16) f16 Vs[64 * 64];
    __shared__ __align__(16) f16 Ps[4][16 * 136];
    int z = blockIdx.z;
    int b = z >> 1, sp = z & 1;
    int h = blockIdx.y, bh = b * 8 + h;
    int Nkh = Nk >> 1;
    int tid = threadIdx.x, lane = tid & 63, wave = tid >> 6;
    int quad = lane >> 4, ln16 = lane & 15;
    int qrow0 = blockIdx.x * 64 + wave * 16;

    f16x8 aq0, aq1;
    {
        const f16* qp = Qh + ((size_t)bh * 2048 + qrow0 + ln16) * 64 + quad * 8;
        aq0 = *(const f16x8*)qp;
        aq1 = *(const f16x8*)(qp + 32);
    }
    f16x8 ones;
#pragma unroll
    for (int j = 0; j < 8; j++) ones[j] = (f16)1.0f;

    float mrun[4];
    f32x4 oacc[4], aol = (f32x4){0.f, 0.f, 0.f, 0.f};
#pragma unroll
    for (int i = 0; i < 4; i++) { mrun[i] = -INFINITY; oacc[i] = (f32x4){0.f, 0.f, 0.f, 0.f}; }

    const f16* kb = Kh + ((size_t)bh * Nk + sp * Nkh) * 64;
    const f16* vb = Vt + (size_t)bh * 64 * Nk + sp * Nkh;

    int L0 = tid, L1 = tid + 256;
    const f16* kg0 = kb + (size_t)(L0 >> 3) * 64 + ((L0 & 7) ^ ((L0 >> 3) & 7)) * 8;
    const f16* kg1 = kb + (size_t)(L1 >> 3) * 64 + ((L1 & 7) ^ ((L1 >> 3) & 7)) * 8;
    const f16* vg0 = vb + (size_t)(L0 >> 3) * Nk + ((L0 & 7) ^ ((L0 >> 3) & 7)) * 8;
    const f16* vg1 = vb + (size_t)(L1 >> 3) * Nk + ((L1 & 7) ^ ((L1 >> 3) & 7)) * 8;
    f16* kl0 = Kt + (size_t)L0 * 8; f16* kl1 = Kt + (size_t)L1 * 8;
    f16* vl0 = Vs + (size_t)L0 * 8; f16* vl1 = Vs + (size_t)L1 * 8;

    // hoisted LDS read offsets
    int ko0[4], ko1[4], vo[4][2];
#pragma unroll
    for (int nt = 0; nt < 4; nt++) {
        int key = nt * 16 + ln16;
        ko0[nt] = key * 64 + (quad ^ (key & 7)) * 8;
        ko1[nt] = key * 64 + ((4 + quad) ^ (key & 7)) * 8;
    }
#pragma unroll
    for (int dt = 0; dt < 4; dt++) {
        int d = dt * 16 + ln16;
#pragma unroll
        for (int kk = 0; kk < 2; kk++)
            vo[dt][kk] = d * 64 + (((kk * 4 + quad) ^ (d & 7)) * 8);
    }
    int pr0 = ln16 * 136 + quad * 8, pr1 = pr0 + 32;

    for (int kt = 0; kt < Nkh; kt += 64) {
        __syncthreads();
        gl_lds16(kg0, kl0); gl_lds16(kg1, kl1);
        gl_lds16(vg0, vl0); gl_lds16(vg1, vl1);
        __syncthreads();
        kg0 += 64 * 64; kg1 += 64 * 64;
        vg0 += 64; vg1 += 64;

        f32x4 s[4];
#pragma unroll
        for (int nt = 0; nt < 4; nt++) {
            f16x8 kb0 = *(const f16x8*)&Kt[ko0[nt]];
            f16x8 kb1 = *(const f16x8*)&Kt[ko1[nt]];
            f32x4 zz = (f32x4){0.f, 0.f, 0.f, 0.f};
            zz = __builtin_amdgcn_mfma_f32_16x16x32_f16(aq0, kb0, zz, 0, 0, 0);
            zz = __builtin_amdgcn_mfma_f32_16x16x32_f16(aq1, kb1, zz, 0, 0, 0);
            s[nt] = zz;
        }
        float mx[4];
#pragma unroll
        for (int i = 0; i < 4; i++)
            mx[i] = fmaxf(fmaxf(s[0][i], s[1][i]), fmaxf(s[2][i], s[3][i]));
#pragma unroll
        for (int m = 1; m < 16; m <<= 1)
#pragma unroll
            for (int i = 0; i < 4; i++) mx[i] = fmaxf(mx[i], __shfl_xor(mx[i], m, 64));
        float alpha[4];
#pragma unroll
        for (int i = 0; i < 4; i++) {
            float mn = fmaxf(mrun[i], mx[i]);
            alpha[i] = exp2f(mrun[i] - mn);
            mrun[i] = mn;
        }
        f16* pw = &Ps[wave][0];
#pragma unroll
        for (int nt = 0; nt < 4; nt++)
#pragma unroll
            for (int i = 0; i < 4; i++)
                pw[(quad * 4 + i) * 136 + nt * 16 + ln16] = (f16)exp2f(s[nt][i] - mrun[i]);
#pragma unroll
        for (int dt = 0; dt < 4; dt++)
#pragma unroll
            for (int i = 0; i < 4; i++) oacc[dt][i] *= alpha[i];
#pragma unroll
        for (int i = 0; i < 4; i++) aol[i] *= alpha[i];

        f16x8 ap0 = *(const f16x8*)&pw[pr0];
        f16x8 ap1 = *(const f16x8*)&pw[pr1];
        aol = __builtin_amdgcn_mfma_f32_16x16x32_f16(ap0, ones, aol, 0, 0, 0);
        aol = __builtin_amdgcn_mfma_f32_16x16x32_f16(ap1, ones, aol, 0, 0, 0);
#pragma unroll
        for (int dt = 0; dt < 4; dt++) {
            f16x8 vb0 = *(const f16x8*)&Vs[vo[dt][0]];
            f16x8 vb1 = *(const f16x8*)&Vs[vo[dt][1]];
            oacc[dt] = __builtin_amdgcn_mfma_f32_16x16x32_f16(ap0, vb0, oacc[dt], 0, 0, 0);
            oacc[dt] = __builtin_amdgcn_mfma_f32_16x16x32_f16(ap1, vb1, oacc[dt], 0, 0, 0);
        }
    }

    int qb = qrow0 + quad * 4;
    size_t pb = (size_t)(sp * 16 + bh) * 2048;
#pragma unroll
    for (int dt = 0; dt < 4; dt++)
#pragma unroll
        for (int i = 0; i < 4; i++)
            Op[(pb + qb + i) * 64 + dt * 16 + ln16] = (f16)oacc[dt][i];
    if (ln16 == 0) {
#pragma unroll
        for (int i = 0; i < 4; i++) {
            float2 ml; ml.x = mrun[i]; ml.y = aol[i];
            ML[pb + qb + i] = ml;
        }
    }
}

// ---------------------------------------------------------------------------
// Combine the 2 key-splits -> ctx f16 [B*2048][512].  grid 8192 x 256.
// ---------------------------------------------------------------------------
__global__ __launch_bounds__(256)
void attn_combine(const f16* __restrict__ Op, const float2* __restrict__ ML,
                  f16* __restrict__ O)
{
    int t = blockIdx.x * 256 + threadIdx.x;
    int d = t & 63;
    int q = (t >> 6) & 2047;
    int bh = t >> 17;
    int b = bh >> 3, h = bh & 7;
    size_t i0 = (size_t)bh * 2048 + q;
    size_t i1 = (size_t)(16 + bh) * 2048 + q;
    float2 ml0 = ML[i0], ml1 = ML[i1];
    float m = fmaxf(ml0.x, ml1.x);
    float e0 = exp2f(ml0.x - m), e1 = exp2f(ml1.x - m);
    float l = e0 * ml0.y + e1 * ml1.y;
    float o0 = (float)Op[i0 * 64 + d], o1 = (float)Op[i1 * 64 + d];
    float val = (e0 * o0 + e1 * o1) / l;
    O[((size_t)b * 2048 + q) * 512 + h * 64 + d] = (f16)val;
}

// ---------------------------------------------------------------------------
extern "C" void kernel_launch(void* const* d_in, const int* in_sizes, int n_in,
                              void* d_out, int out_size, void* d_ws, size_t ws_size,
                              hipStream_t stream)
{
    (void)in_sizes; (void)n_in; (void)out_size; (void)ws_size;
    const float* x      = (const float*)d_in[0];
    const float* cross  = (const float*)d_in[1];
    const float* ca_wq  = (const float*)d_in[2];
    const float* ca_bq  = (const float*)d_in[3];
    const float* ca_wk  = (const float*)d_in[4];
    const float* ca_bk  = (const float*)d_in[5];
    const float* ca_wv  = (const float*)d_in[6];
    const float* ca_bv  = (const float*)d_in[7];
    const float* ca_wo  = (const float*)d_in[8];
    const float* ca_bo  = (const float*)d_in[9];
    const float* sa_wq  = (const float*)d_in[10];
    const float* sa_bq  = (const float*)d_in[11];
    const float* sa_wk  = (const float*)d_in[12];
    const float* sa_bk  = (const float*)d_in[13];
    const float* sa_wv  = (const float*)d_in[14];
    const float* sa_bv  = (const float*)d_in[15];
    const float* sa_wo  = (const float*)d_in[16];
    const float* sa_bo  = (const float*)d_in[17];
    const float* ln1_g  = (const float*)d_in[18];
    const float* ln1_b  = (const float*)d_in[19];
    const float* ln2_g  = (const float*)d_in[20];
    const float* ln2_b  = (const float*)d_in[21];
    const float* mlp_w1 = (const float*)d_in[22];
    const float* mlp_b1 = (const float*)d_in[23];
    const float* mlp_w2 = (const float*)d_in[24];
    const float* mlp_b2 = (const float*)d_in[25];
    float* out = (float*)d_out;

    // ---- workspace layout ----
    float* XC = (float*)d_ws;            // 2M f32
    float* Yb = XC + 2097152;            // 2M f32
    f16* fb   = (f16*)(Yb + 2097152);
    f16* xh     = fb;                    // 2M
    f16* crossh = xh + 2097152;          // 4M
    f16* xnh    = crossh + 4194304;      // 2M
    f16* xn2h   = xnh + 2097152;         // 2M
    f16* Qh     = xn2h + 2097152;        // 2M
    f16* Kh     = Qh + 2097152;          // 4M
    f16* Vh     = Kh + 4194304;          // 4M  (reused as attention partials Op)
    f16* Vtb    = Vh + 4194304;          // 4M
    f16* ctxh   = Vtb + 4194304;         // 2M
    f16* h1h    = ctxh + 2097152;        // 8M
    f16* t_caq  = h1h + 8388608;
    f16* t_cak  = t_caq + 262144;
    f16* t_cav  = t_cak + 262144;
    f16* t_cao  = t_cav + 262144;
    f16* t_saq  = t_cao + 262144;
    f16* t_sak  = t_saq + 262144;
    f16* t_sav  = t_sak + 262144;
    f16* t_sao  = t_sav + 262144;
    f16* t_w1   = t_sao + 262144;        // 1M
    f16* t_w2   = t_w1 + 1048576;        // 1M
    float2* ML  = (float2*)(t_w2 + 1048576);   // 64K float2

    dim3 tb(32, 8);
    P8 p8;
    p8.s[0] = ca_wq; p8.d[0] = t_caq;
    p8.s[1] = ca_wk; p8.d[1] = t_cak;
    p8.s[2] = ca_wv; p8.d[2] = t_cav;
    p8.s[3] = ca_wo; p8.d[3] = t_cao;
    p8.s[4] = sa_wq; p8.d[4] = t_saq;
    p8.s[5] = sa_wk; p8.d[5] = t_sak;
    p8.s[6] = sa_wv; p8.d[6] = t_sav;
    p8.s[7] = sa_wo; p8.d[7] = t_sao;
    transpose_cvt8<<<dim3(16, 16, 8), tb, 0, stream>>>(p8);
    transpose_cvt<<<dim3(64, 16), tb, 0, stream>>>(mlp_w1, t_w1, 512, 2048);
    transpose_cvt<<<dim3(16, 64), tb, 0, stream>>>(mlp_w2, t_w2, 2048, 512);
    cvt_f16_kernel<<<2048, 256, 0, stream>>>(x, xh);
    cvt_f16_kernel<<<4096, 256, 0, stream>>>(cross, crossh);

    // a) cross-attention
    gemm64<<<dim3(8, 64), 256, 0, stream>>>(xh, t_caq, ca_bq, nullptr, nullptr, Qh,
                                            512, 512, 11, QSCALE);
    gemm_f16<<<dim3(8, 64), 256, 0, stream>>>(crossh, t_cak, ca_bk, ca_bv, nullptr, nullptr,
        nullptr, nullptr, Kh, Vh, nullptr, 1024, 512, 12, 1, 0, 1.0f);
    transpose_v<<<dim3(64, 16), 256, 0, stream>>>(Vh, Vtb, 4096);
    attention_split<<<dim3(32, 8, 4), 256, 0, stream>>>(Qh, Kh, Vtb, Vh, ML, 4096);
    attn_combine<<<8192, 256, 0, stream>>>(Vh, ML, ctxh);
    gemm64<<<dim3(8, 64), 256, 0, stream>>>(ctxh, t_cao, ca_bo, nullptr, XC, nullptr,
                                            512, 512, 11, 1.0f);
    // b,c) LN1 + self-attention (fused QKV, Q pre-scaled)
    layernorm_f16<<<4096, 128, 0, stream>>>(XC, ln1_g, ln1_b, xnh);
    gemm_f16<<<dim3(12, 32), 256, 0, stream>>>(xnh, t_saq, sa_bq, sa_bk, sa_bv, nullptr,
        nullptr, nullptr, Qh, Kh, Vh, 1536, 512, 11, 1, 0, QSCALE);
    transpose_v<<<dim3(32, 16), 256, 0, stream>>>(Vh, Vtb, 2048);
    attention_split<<<dim3(32, 8, 4), 256, 0, stream>>>(Qh, Kh, Vtb, Vh, ML, 2048);
    attn_combine<<<8192, 256, 0, stream>>>(Vh, ML, ctxh);
    // d) y = xc + xs
    gemm64<<<dim3(8, 64), 256, 0, stream>>>(ctxh, t_sao, sa_bo, XC, Yb, nullptr,
                                            512, 512, 11, 1.0f);
    // e,f) LN2 + GELU MLP
    layernorm_f16<<<4096, 128, 0, stream>>>(Yb, ln2_g, ln2_b, xn2h);
    gemm_f16<<<dim3(16, 32), 256, 0, stream>>>(xn2h, t_w1, mlp_b1, nullptr, nullptr, nullptr,
        nullptr, h1h, nullptr, nullptr, nullptr, 2048, 512, 11, 0, 1, 1.0f);
    // g) out = y + h1 @ w2 + b2
    gemm64<<<dim3(8, 64), 256, 0, stream>>>(h1h, t_w2, mlp_b2, Yb, out, nullptr,
                                            512, 2048, 11, 1.0f);
}